// Round 1
// baseline (66779.254 us; speedup 1.0000x reference)
//
#include <hip/hip_runtime.h>
#include <cstddef>
#include <cstdint>

#define DIM 128
#define NROUNDS 120
#define NNZ_CAP (1 << 20)

__device__ __forceinline__ float sigf(float x) { return 1.f / (1.f + __expf(-x)); }
__device__ __forceinline__ float tanh_fast(float x) { return 2.f / (1.f + __expf(-2.f * x)) - 1.f; }

// ---------------- sparse build ----------------
__global__ void count_nz_kernel(const float* __restrict__ adj, int* __restrict__ row_cnt,
                                int* __restrict__ col_cnt, int ncols) {
  int i = blockIdx.x;
  int j = blockIdx.y * blockDim.x + threadIdx.x;
  bool nz = (j < ncols) && (adj[(size_t)i * ncols + j] != 0.f);
  unsigned long long m = __ballot(nz);
  if ((threadIdx.x & 63) == 0) {
    int c = __popcll(m);
    if (c) atomicAdd(&row_cnt[i], c);
  }
  if (nz) atomicAdd(&col_cnt[j], 1);
}

__global__ void scan_kernel(const int* __restrict__ cnt, int* __restrict__ ptr, int n) {
  __shared__ int sdata[256];
  int t = threadIdx.x;
  int per = (n + 255) / 256;
  int beg = t * per;
  int end = beg + per; if (end > n) end = n;
  int local = 0;
  for (int i = beg; i < end; ++i) local += cnt[i];
  sdata[t] = local;
  __syncthreads();
  for (int off = 1; off < 256; off <<= 1) {
    int v = (t >= off) ? sdata[t - off] : 0;
    __syncthreads();
    sdata[t] += v;
    __syncthreads();
  }
  int run = sdata[t] - local;
  for (int i = beg; i < end; ++i) { ptr[i] = run; run += cnt[i]; }
  if (t == 255) ptr[n] = sdata[255];
}

__global__ void fill_nz_kernel(const float* __restrict__ adj, const int* __restrict__ row_ptr,
                               const int* __restrict__ col_ptr, int* __restrict__ row_fill,
                               int* __restrict__ col_fill, int* __restrict__ col_idx,
                               int* __restrict__ row_idx, int ncols) {
  int i = blockIdx.x;
  int j = blockIdx.y * blockDim.x + threadIdx.x;
  if (j >= ncols) return;
  if (adj[(size_t)i * ncols + j] != 0.f) {
    int r = atomicAdd(&row_fill[i], 1);
    col_idx[row_ptr[i] + r] = j;
    int c = atomicAdd(&col_fill[j], 1);
    row_idx[col_ptr[j] + c] = i;
  }
}

// ---------------- init ----------------
__global__ void init_hc_kernel(const int* __restrict__ values, const float* __restrict__ tW,
                               const float* __restrict__ tb, const float* __restrict__ fW,
                               const float* __restrict__ fb, float* __restrict__ h,
                               float* __restrict__ c, int N) {
  int idx = blockIdx.x * blockDim.x + threadIdx.x;
  if (idx >= N * DIM) return;
  int row = idx >> 7, col = idx & (DIM - 1);
  float tv = tW[col] + tb[col];
  float fv = fW[col] + fb[col];
  h[idx] = (values[row] == 1) ? tv : fv;
  c[idx] = 0.f;
}

// ---------------- dense tile GEMM: acc[4][4] += S(32x128 LDS) x W^T ----------------
__device__ __forceinline__ void tile_gemm(const float* S, const float* __restrict__ W,
                                          int colB, int rowB, float acc[4][4]) {
#pragma unroll 4
  for (int kc = 0; kc < DIM; kc += 4) {
    float4 xv[4], wv[4];
#pragma unroll
    for (int r = 0; r < 4; ++r) xv[r] = *(const float4*)(S + (rowB + r) * DIM + kc);
#pragma unroll
    for (int c = 0; c < 4; ++c) wv[c] = *(const float4*)(W + (size_t)(colB + c) * DIM + kc);
#pragma unroll
    for (int r = 0; r < 4; ++r)
#pragma unroll
      for (int c = 0; c < 4; ++c)
        acc[r][c] += xv[r].x * wv[c].x + xv[r].y * wv[c].y + xv[r].z * wv[c].z + xv[r].w * wv[c].w;
  }
}

__device__ __forceinline__ void layer_lds(const float* Sin, float* Sout,
                                          const float* __restrict__ W, const float* __restrict__ B,
                                          bool relu, int colB, int rowB) {
  float acc[4][4];
#pragma unroll
  for (int r = 0; r < 4; ++r)
#pragma unroll
    for (int cc = 0; cc < 4; ++cc) acc[r][cc] = B[colB + cc];
  tile_gemm(Sin, W, colB, rowB, acc);
#pragma unroll
  for (int r = 0; r < 4; ++r) {
    float4 v;
    v.x = acc[r][0]; v.y = acc[r][1]; v.z = acc[r][2]; v.w = acc[r][3];
    if (relu) { v.x = fmaxf(v.x, 0.f); v.y = fmaxf(v.y, 0.f); v.z = fmaxf(v.z, 0.f); v.w = fmaxf(v.w, 0.f); }
    *(float4*)&Sout[(rowB + r) * DIM + colB] = v;
  }
  __syncthreads();
}

// ---------------- fused 3-layer MLP (relu, relu, linear) ----------------
__global__ __launch_bounds__(256) void mlp3_kernel(
    const float* __restrict__ X, int M,
    const float* __restrict__ W1, const float* __restrict__ b1,
    const float* __restrict__ W2, const float* __restrict__ b2,
    const float* __restrict__ W3, const float* __restrict__ b3,
    float* __restrict__ out) {
  __shared__ float Xs[32 * DIM];
  __shared__ float Ys[32 * DIM];
  int tid = threadIdx.x;
  int rb = blockIdx.x * 32;
  int mrows = M - rb; if (mrows > 32) mrows = 32;
  {
    const float4* src = (const float4*)(X + (size_t)rb * DIM);
    float4* dst = (float4*)Xs;
    int nf4 = mrows * (DIM / 4);
    for (int t = tid; t < 32 * (DIM / 4); t += 256) {
      float4 v;
      if (t < nf4) v = src[t];
      else { v.x = v.y = v.z = v.w = 0.f; }
      dst[t] = v;
    }
  }
  __syncthreads();
  int tx = tid & 31, ty = tid >> 5;
  int colB = tx * 4, rowB = ty * 4;

  layer_lds(Xs, Ys, W1, b1, true, colB, rowB);
  layer_lds(Ys, Xs, W2, b2, true, colB, rowB);

  float acc[4][4];
#pragma unroll
  for (int r = 0; r < 4; ++r)
#pragma unroll
    for (int cc = 0; cc < 4; ++cc) acc[r][cc] = b3[colB + cc];
  tile_gemm(Xs, W3, colB, rowB, acc);
#pragma unroll
  for (int r = 0; r < 4; ++r) {
    int gr = rb + rowB + r;
    if (gr < M) {
      float4 v;
      v.x = acc[r][0]; v.y = acc[r][1]; v.z = acc[r][2]; v.w = acc[r][3];
      *(float4*)&out[(size_t)gr * DIM + colB] = v;
    }
  }
}

// ---------------- SpMM (binary adjacency): out[row] = sum of src[idx] ----------------
__global__ __launch_bounds__(256) void spmm_kernel(const int* __restrict__ ptr,
                                                   const int* __restrict__ idx,
                                                   const float* __restrict__ src,
                                                   float* __restrict__ out, int M) {
  int w = (blockIdx.x * 256 + threadIdx.x) >> 6;
  if (w >= M) return;
  int lane2 = (threadIdx.x & 63) * 2;
  int s = ptr[w], e = ptr[w + 1];
  float a0 = 0.f, a1 = 0.f;
  for (int p = s; p < e; ++p) {
    const float* rp = src + (size_t)idx[p] * DIM + lane2;
    a0 += rp[0]; a1 += rp[1];
  }
  float* op = out + (size_t)w * DIM + lane2;
  op[0] = a0; op[1] = a1;
}

// ---------------- fused LSTM cell (gates GEMM + elementwise, in-place h,c) ----------------
__device__ __forceinline__ void gate_gemm(const float* Xs, const float* Hs,
                                          const float* __restrict__ Wih, const float* __restrict__ Whh,
                                          const float* __restrict__ bih, const float* __restrict__ bhh,
                                          int g, int colB, int rowB, float acc[4][4]) {
#pragma unroll
  for (int r = 0; r < 4; ++r)
#pragma unroll
    for (int cc = 0; cc < 4; ++cc)
      acc[r][cc] = bih[g * DIM + colB + cc] + bhh[g * DIM + colB + cc];
  tile_gemm(Xs, Wih + (size_t)g * DIM * DIM, colB, rowB, acc);
  tile_gemm(Hs, Whh + (size_t)g * DIM * DIM, colB, rowB, acc);
}

__global__ __launch_bounds__(256) void lstm_kernel(
    const float* __restrict__ Xin, float* __restrict__ hbuf, float* __restrict__ cbuf, int M,
    const float* __restrict__ Wih, const float* __restrict__ Whh,
    const float* __restrict__ bih, const float* __restrict__ bhh) {
  __shared__ float Xs[32 * DIM];
  __shared__ float Hs[32 * DIM];
  int tid = threadIdx.x;
  int rb = blockIdx.x * 32;
  int mrows = M - rb; if (mrows > 32) mrows = 32;
  {
    const float4* sx = (const float4*)(Xin + (size_t)rb * DIM);
    const float4* sh = (const float4*)(hbuf + (size_t)rb * DIM);
    float4* dx = (float4*)Xs;
    float4* dh = (float4*)Hs;
    int nf4 = mrows * (DIM / 4);
    for (int t = tid; t < 32 * (DIM / 4); t += 256) {
      float4 vx, vh;
      if (t < nf4) { vx = sx[t]; vh = sh[t]; }
      else { vx.x = vx.y = vx.z = vx.w = 0.f; vh = vx; }
      dx[t] = vx; dh[t] = vh;
    }
  }
  __syncthreads();
  int tx = tid & 31, ty = tid >> 5;
  int colB = tx * 4, rowB = ty * 4;

  float acc[4][4], prod[4][4], cn[4][4];

  // gate i (0)
  gate_gemm(Xs, Hs, Wih, Whh, bih, bhh, 0, colB, rowB, acc);
#pragma unroll
  for (int r = 0; r < 4; ++r)
#pragma unroll
    for (int cc = 0; cc < 4; ++cc) prod[r][cc] = sigf(acc[r][cc]);

  // gate g (2)
  gate_gemm(Xs, Hs, Wih, Whh, bih, bhh, 2, colB, rowB, acc);
#pragma unroll
  for (int r = 0; r < 4; ++r)
#pragma unroll
    for (int cc = 0; cc < 4; ++cc) prod[r][cc] *= tanh_fast(acc[r][cc]);

  // gate f (1): c_new = sig(f)*c_old + sig(i)*tanh(g)
  gate_gemm(Xs, Hs, Wih, Whh, bih, bhh, 1, colB, rowB, acc);
#pragma unroll
  for (int r = 0; r < 4; ++r) {
    int gr = rb + rowB + r;
    float4 cold;
    if (gr < M) cold = *(const float4*)&cbuf[(size_t)gr * DIM + colB];
    else { cold.x = cold.y = cold.z = cold.w = 0.f; }
    cn[r][0] = sigf(acc[r][0]) * cold.x + prod[r][0];
    cn[r][1] = sigf(acc[r][1]) * cold.y + prod[r][1];
    cn[r][2] = sigf(acc[r][2]) * cold.z + prod[r][2];
    cn[r][3] = sigf(acc[r][3]) * cold.w + prod[r][3];
    if (gr < M) {
      float4 v; v.x = cn[r][0]; v.y = cn[r][1]; v.z = cn[r][2]; v.w = cn[r][3];
      *(float4*)&cbuf[(size_t)gr * DIM + colB] = v;
    }
  }

  // gate o (3): h_new = sig(o)*tanh(c_new)
  gate_gemm(Xs, Hs, Wih, Whh, bih, bhh, 3, colB, rowB, acc);
#pragma unroll
  for (int r = 0; r < 4; ++r) {
    int gr = rb + rowB + r;
    if (gr < M) {
      float4 v;
      v.x = sigf(acc[r][0]) * tanh_fast(cn[r][0]);
      v.y = sigf(acc[r][1]) * tanh_fast(cn[r][1]);
      v.z = sigf(acc[r][2]) * tanh_fast(cn[r][2]);
      v.w = sigf(acc[r][3]) * tanh_fast(cn[r][3]);
      *(float4*)&hbuf[(size_t)gr * DIM + colB] = v;
    }
  }
}

// ---------------- final vote MLP (128->128 relu, 128->128 relu, 128->1) ----------------
__global__ __launch_bounds__(256) void vote_kernel(
    const float* __restrict__ X, int M,
    const float* __restrict__ W1, const float* __restrict__ b1,
    const float* __restrict__ W2, const float* __restrict__ b2,
    const float* __restrict__ W3, const float* __restrict__ b3,
    float* __restrict__ out) {
  __shared__ float Xs[32 * DIM];
  __shared__ float Ys[32 * DIM];
  int tid = threadIdx.x;
  int rb = blockIdx.x * 32;
  int mrows = M - rb; if (mrows > 32) mrows = 32;
  {
    const float4* src = (const float4*)(X + (size_t)rb * DIM);
    float4* dst = (float4*)Xs;
    int nf4 = mrows * (DIM / 4);
    for (int t = tid; t < 32 * (DIM / 4); t += 256) {
      float4 v;
      if (t < nf4) v = src[t];
      else { v.x = v.y = v.z = v.w = 0.f; }
      dst[t] = v;
    }
  }
  __syncthreads();
  int tx = tid & 31, ty = tid >> 5;
  int colB = tx * 4, rowB = ty * 4;
  layer_lds(Xs, Ys, W1, b1, true, colB, rowB);
  layer_lds(Ys, Xs, W2, b2, true, colB, rowB);
  if (tid < 32) {
    int gr = rb + tid;
    if (gr < M) {
      float s = b3[0];
      for (int k = 0; k < DIM; ++k) s += Xs[tid * DIM + k] * W3[k];
      out[gr] = s;
    }
  }
}

extern "C" void kernel_launch(void* const* d_in, const int* in_sizes, int n_in,
                              void* d_out, int out_size, void* d_ws, size_t ws_size,
                              hipStream_t stream) {
  const float* adj    = (const float*)d_in[0];
  const int*   values = (const int*)d_in[1];
  const int N       = in_sizes[1];                  // 9000
  const int n_nodes = in_sizes[0] / N;              // 8000
  const int n_vars  = N - n_nodes;                  // 1000

  const float* true_W  = (const float*)d_in[3];
  const float* true_b  = (const float*)d_in[4];
  const float* false_W = (const float*)d_in[5];
  const float* false_b = (const float*)d_in[6];
  const float* cm_W1 = (const float*)d_in[7];
  const float* cm_b1 = (const float*)d_in[8];
  const float* cm_W2 = (const float*)d_in[9];
  const float* cm_b2 = (const float*)d_in[10];
  const float* cm_W3 = (const float*)d_in[11];
  const float* cm_b3 = (const float*)d_in[12];
  const float* pm_W1 = (const float*)d_in[13];
  const float* pm_b1 = (const float*)d_in[14];
  const float* pm_W2 = (const float*)d_in[15];
  const float* pm_b2 = (const float*)d_in[16];
  const float* pm_W3 = (const float*)d_in[17];
  const float* pm_b3 = (const float*)d_in[18];
  const float* vv_W1 = (const float*)d_in[19];
  const float* vv_b1 = (const float*)d_in[20];
  const float* vv_W2 = (const float*)d_in[21];
  const float* vv_b2 = (const float*)d_in[22];
  const float* vv_W3 = (const float*)d_in[23];
  const float* vv_b3 = (const float*)d_in[24];
  const float* vu_Wih = (const float*)d_in[25];
  const float* vu_Whh = (const float*)d_in[26];
  const float* vu_bih = (const float*)d_in[27];
  const float* vu_bhh = (const float*)d_in[28];
  const float* nu_Wih = (const float*)d_in[29];
  const float* nu_Whh = (const float*)d_in[30];
  const float* nu_bih = (const float*)d_in[31];
  const float* nu_bhh = (const float*)d_in[32];

  uintptr_t p = (uintptr_t)d_ws;
  auto take = [&](size_t bytes) -> void* {
    uintptr_t cur = (p + 255) & ~(uintptr_t)255;
    p = cur + bytes;
    return (void*)cur;
  };
  float* h  = (float*)take((size_t)N * DIM * sizeof(float));
  float* cb = (float*)take((size_t)N * DIM * sizeof(float));
  float* va = (float*)take((size_t)N * DIM * sizeof(float));
  float* vb = (float*)take((size_t)N * DIM * sizeof(float));
  int* row_ptr = (int*)take((size_t)(n_nodes + 1) * sizeof(int));
  int* col_ptr = (int*)take((size_t)(N + 1) * sizeof(int));
  int* cnts    = (int*)take((size_t)2 * (n_nodes + N) * sizeof(int));
  int* row_cnt  = cnts;
  int* col_cnt  = cnts + n_nodes;
  int* row_fill = cnts + n_nodes + N;
  int* col_fill = cnts + 2 * n_nodes + N;
  int* col_idx = (int*)take((size_t)NNZ_CAP * sizeof(int));
  int* row_idx = (int*)take((size_t)NNZ_CAP * sizeof(int));

  hipMemsetAsync(cnts, 0, (size_t)2 * (n_nodes + N) * sizeof(int), stream);
  dim3 cgrid(n_nodes, (N + 255) / 256);
  count_nz_kernel<<<cgrid, 256, 0, stream>>>(adj, row_cnt, col_cnt, N);
  scan_kernel<<<1, 256, 0, stream>>>(row_cnt, row_ptr, n_nodes);
  scan_kernel<<<1, 256, 0, stream>>>(col_cnt, col_ptr, N);
  fill_nz_kernel<<<cgrid, 256, 0, stream>>>(adj, row_ptr, col_ptr, row_fill, col_fill,
                                            col_idx, row_idx, N);
  init_hc_kernel<<<(N * DIM + 255) / 256, 256, 0, stream>>>(values, true_W, true_b,
                                                            false_W, false_b, h, cb, N);

  int mb_N = (N + 31) / 32, mb_n = (n_nodes + 31) / 32;
  int sb_n = (n_nodes + 3) / 4, sb_N = (N + 3) / 4;
  for (int r = 0; r < NROUNDS; ++r) {
    mlp3_kernel<<<mb_N, 256, 0, stream>>>(h, N, cm_W1, cm_b1, cm_W2, cm_b2, cm_W3, cm_b3, va);
    spmm_kernel<<<sb_n, 256, 0, stream>>>(row_ptr, col_idx, va, vb, n_nodes);
    lstm_kernel<<<mb_n, 256, 0, stream>>>(vb, h, cb, n_nodes, vu_Wih, vu_Whh, vu_bih, vu_bhh);
    mlp3_kernel<<<mb_n, 256, 0, stream>>>(h, n_nodes, pm_W1, pm_b1, pm_W2, pm_b2, pm_W3, pm_b3, va);
    spmm_kernel<<<sb_N, 256, 0, stream>>>(col_ptr, row_idx, va, vb, N);
    lstm_kernel<<<mb_N, 256, 0, stream>>>(vb, h, cb, N, nu_Wih, nu_Whh, nu_bih, nu_bhh);
  }
  vote_kernel<<<(n_vars + 31) / 32, 256, 0, stream>>>(h + (size_t)n_nodes * DIM, n_vars,
      vv_W1, vv_b1, vv_W2, vv_b2, vv_W3, vv_b3, (float*)d_out);
}

// Round 2
// 15527.991 us; speedup vs baseline: 4.3006x; 4.3006x over previous
//
#include <hip/hip_runtime.h>
#include <cstddef>
#include <cstdint>

#define DIM 128
#define NROUNDS 120
#define NNZ_CAP (1 << 20)

typedef _Float16 half8 __attribute__((ext_vector_type(8)));
typedef float f32x16 __attribute__((ext_vector_type(16)));

__device__ __forceinline__ float sigf(float x) { return 1.f / (1.f + __expf(-x)); }
__device__ __forceinline__ float tanh_fast(float x) { return 2.f / (1.f + __expf(-2.f * x)) - 1.f; }

// ---------------- sparse build ----------------
__global__ void count_nz_kernel(const float* __restrict__ adj, int* __restrict__ row_cnt,
                                int* __restrict__ col_cnt, int ncols) {
  int i = blockIdx.x;
  int j = blockIdx.y * blockDim.x + threadIdx.x;
  bool nz = (j < ncols) && (adj[(size_t)i * ncols + j] != 0.f);
  unsigned long long m = __ballot(nz);
  if ((threadIdx.x & 63) == 0) {
    int c = __popcll(m);
    if (c) atomicAdd(&row_cnt[i], c);
  }
  if (nz) atomicAdd(&col_cnt[j], 1);
}

__global__ void scan_kernel(const int* __restrict__ cnt, int* __restrict__ ptr, int n) {
  __shared__ int sdata[256];
  int t = threadIdx.x;
  int per = (n + 255) / 256;
  int beg = t * per;
  int end = beg + per; if (end > n) end = n;
  int local = 0;
  for (int i = beg; i < end; ++i) local += cnt[i];
  sdata[t] = local;
  __syncthreads();
  for (int off = 1; off < 256; off <<= 1) {
    int v = (t >= off) ? sdata[t - off] : 0;
    __syncthreads();
    sdata[t] += v;
    __syncthreads();
  }
  int run = sdata[t] - local;
  for (int i = beg; i < end; ++i) { ptr[i] = run; run += cnt[i]; }
  if (t == 255) ptr[n] = sdata[255];
}

__global__ void fill_nz_kernel(const float* __restrict__ adj, const int* __restrict__ row_ptr,
                               const int* __restrict__ col_ptr, int* __restrict__ row_fill,
                               int* __restrict__ col_fill, int* __restrict__ col_idx,
                               int* __restrict__ row_idx, int ncols) {
  int i = blockIdx.x;
  int j = blockIdx.y * blockDim.x + threadIdx.x;
  if (j >= ncols) return;
  if (adj[(size_t)i * ncols + j] != 0.f) {
    int r = atomicAdd(&row_fill[i], 1);
    col_idx[row_ptr[i] + r] = j;
    int c = atomicAdd(&col_fill[j], 1);
    row_idx[col_ptr[j] + c] = i;
  }
}

// ---------------- weight packing into MFMA B-fragment order (split f16) ----------------
// B[k][n] = W[n][k]; 32x32x16 B-fragment: lane L holds k = ks*16 + (L>>5)*8 + j, n = nt*32 + (L&31)
// packed index = ((nt*8 + ks)*64 + L)*8 + j
__global__ void pack_w_kernel(const float* __restrict__ src, int out_dim,
                              _Float16* __restrict__ dh, _Float16* __restrict__ dl) {
  int idx = blockIdx.x * 256 + threadIdx.x;
  if (idx >= out_dim * DIM) return;
  int n = idx >> 7, k = idx & 127;
  float x = src[idx];
  _Float16 hi = (_Float16)x;
  _Float16 lo = (_Float16)(x - (float)hi);
  int nt = n >> 5, ks = k >> 4;
  int L = ((k >> 3) & 1) * 32 + (n & 31);
  int j = k & 7;
  int dst = ((nt * 8 + ks) * 64 + L) * 8 + j;
  dh[dst] = hi; dl[dst] = lo;
}

// ---------------- init ----------------
__global__ void init_hc_kernel(const int* __restrict__ values, const float* __restrict__ tW,
                               const float* __restrict__ tb, const float* __restrict__ fW,
                               const float* __restrict__ fb, float* __restrict__ h,
                               float* __restrict__ c, int N) {
  int idx = blockIdx.x * blockDim.x + threadIdx.x;
  if (idx >= N * DIM) return;
  int row = idx >> 7, col = idx & (DIM - 1);
  float tv = tW[col] + tb[col];
  float fv = fW[col] + fb[col];
  h[idx] = (values[row] == 1) ? tv : fv;
  c[idx] = 0.f;
}

// ---------------- LDS layout: row-major 32x128 halves, 16B-chunk XOR swizzle ----------------
__device__ __forceinline__ int sw_idx(int m, int k) {
  return (m << 7) + (((((k >> 3) ^ (m & 15))) << 3) | (k & 7));
}

// stage 32 fp32 rows -> split f16 LDS
__device__ __forceinline__ void stage_rows(const float* __restrict__ src, int M, int rb,
                                           _Float16* Sh, _Float16* Sl, int tid) {
  for (int t = tid; t < 32 * 32; t += 256) {
    int r = t >> 5, q = t & 31;
    int row = rb + r;
    float4 v;
    if (row < M) v = *(const float4*)(src + (size_t)row * DIM + q * 4);
    else { v.x = v.y = v.z = v.w = 0.f; }
    int a = sw_idx(r, q * 4);
    float vv[4] = {v.x, v.y, v.z, v.w};
#pragma unroll
    for (int e = 0; e < 4; ++e) {
      _Float16 hi = (_Float16)vv[e];
      Sh[a + e] = hi;
      Sl[a + e] = (_Float16)(vv[e] - (float)hi);
    }
  }
}

// one 32x32 output tile over K=128, split-f16 (3 MFMAs per k-step)
__device__ __forceinline__ f32x16 gemm_tile(const _Float16* Sh, const _Float16* Sl,
                                            const _Float16* __restrict__ Bh,
                                            const _Float16* __restrict__ Bl,
                                            int nt, int lane, f32x16 acc) {
  int m = lane & 31, hf = lane >> 5;
#pragma unroll
  for (int ks = 0; ks < 8; ++ks) {
    int a_off = (m << 7) + ((((ks * 2 + hf) ^ (m & 15))) << 3);
    half8 ah = *(const half8*)(Sh + a_off);
    half8 al = *(const half8*)(Sl + a_off);
    int boff = ((nt * 8 + ks) * 64 + lane) * 8;
    half8 bh = *(const half8*)(Bh + boff);
    half8 bl = *(const half8*)(Bl + boff);
    acc = __builtin_amdgcn_mfma_f32_32x32x16_f16(ah, bh, acc, 0, 0, 0);
    acc = __builtin_amdgcn_mfma_f32_32x32x16_f16(ah, bl, acc, 0, 0, 0);
    acc = __builtin_amdgcn_mfma_f32_32x32x16_f16(al, bh, acc, 0, 0, 0);
  }
  return acc;
}

// C/D (col=lane&31, row=(reg&3)+8*(reg>>2)+4*(lane>>5)) -> split f16 LDS row-major
__device__ __forceinline__ void write_cd_lds(f32x16 acc, _Float16* Dh, _Float16* Dl,
                                             int nt, int lane, bool relu) {
  int col = (nt << 5) + (lane & 31);
  int rbase = (lane >> 5) << 2;
#pragma unroll
  for (int reg = 0; reg < 16; ++reg) {
    int row = (reg & 3) + ((reg >> 2) << 3) + rbase;
    float x = acc[reg];
    if (relu) x = fmaxf(x, 0.f);
    _Float16 hi = (_Float16)x;
    int a = sw_idx(row, col);
    Dh[a] = hi;
    Dl[a] = (_Float16)(x - (float)hi);
  }
}

// ---------------- fused 3-layer MLP via MFMA ----------------
__global__ __launch_bounds__(256) void mlp3_mfma(
    const float* __restrict__ X, int M,
    const _Float16* __restrict__ W1h, const _Float16* __restrict__ W1l, const float* __restrict__ b1,
    const _Float16* __restrict__ W2h, const _Float16* __restrict__ W2l, const float* __restrict__ b2,
    const _Float16* __restrict__ W3h, const _Float16* __restrict__ W3l, const float* __restrict__ b3,
    float* __restrict__ out) {
  __shared__ _Float16 Ah[4096], Al[4096], Bh2[4096], Bl2[4096];
  int tid = threadIdx.x;
  int rb = blockIdx.x << 5;
  stage_rows(X, M, rb, Ah, Al, tid);
  __syncthreads();
  int lane = tid & 63, w = tid >> 6;
  int colw = (w << 5) + (lane & 31);
  f32x16 acc;
  float bv;

  bv = b1[colw];
#pragma unroll
  for (int i = 0; i < 16; ++i) acc[i] = bv;
  acc = gemm_tile(Ah, Al, W1h, W1l, w, lane, acc);
  write_cd_lds(acc, Bh2, Bl2, w, lane, true);
  __syncthreads();

  bv = b2[colw];
#pragma unroll
  for (int i = 0; i < 16; ++i) acc[i] = bv;
  acc = gemm_tile(Bh2, Bl2, W2h, W2l, w, lane, acc);
  write_cd_lds(acc, Ah, Al, w, lane, true);
  __syncthreads();

  bv = b3[colw];
#pragma unroll
  for (int i = 0; i < 16; ++i) acc[i] = bv;
  acc = gemm_tile(Ah, Al, W3h, W3l, w, lane, acc);

  int rbase = (lane >> 5) << 2;
#pragma unroll
  for (int reg = 0; reg < 16; ++reg) {
    int row = rb + (reg & 3) + ((reg >> 2) << 3) + rbase;
    if (row < M) out[(size_t)row * DIM + colw] = acc[reg];
  }
}

// ---------------- fused SpMM-gather + LSTM cell via MFMA ----------------
__global__ __launch_bounds__(256) void lstm_mfma(
    const int* __restrict__ ptr, const int* __restrict__ nzidx, const float* __restrict__ va,
    float* __restrict__ hbuf, float* __restrict__ cbuf, int M,
    const _Float16* __restrict__ Wxh, const _Float16* __restrict__ Wxl,
    const _Float16* __restrict__ Whh, const _Float16* __restrict__ Whl,
    const float* __restrict__ bih, const float* __restrict__ bhh) {
  __shared__ _Float16 Xh[4096], Xl[4096], Hh[4096], Hl[4096];
  int tid = threadIdx.x;
  int rb = blockIdx.x << 5;
  stage_rows(hbuf, M, rb, Hh, Hl, tid);
  // gather X = sum of va rows (binary SpMM) for this block's 32 rows
  {
    int r = tid >> 3, seg = tid & 7;
    int row = rb + r;
    float a[16];
#pragma unroll
    for (int e = 0; e < 16; ++e) a[e] = 0.f;
    if (row < M) {
      int s = ptr[row], e_ = ptr[row + 1];
      for (int p = s; p < e_; ++p) {
        const float* src = va + (size_t)nzidx[p] * DIM + seg * 16;
#pragma unroll
        for (int q = 0; q < 4; ++q) {
          float4 v = *(const float4*)(src + q * 4);
          a[q * 4 + 0] += v.x; a[q * 4 + 1] += v.y;
          a[q * 4 + 2] += v.z; a[q * 4 + 3] += v.w;
        }
      }
    }
    int k0 = seg * 16;
#pragma unroll
    for (int e = 0; e < 16; ++e) {
      int aidx = sw_idx(r, k0 + e);
      _Float16 hi = (_Float16)a[e];
      Xh[aidx] = hi;
      Xl[aidx] = (_Float16)(a[e] - (float)hi);
    }
  }
  __syncthreads();

  int lane = tid & 63, w = tid >> 6;
  int m = lane & 31, hf = lane >> 5;
  f32x16 acc[4];
#pragma unroll
  for (int g = 0; g < 4; ++g) {
    int col = (g << 7) + (w << 5) + (lane & 31);
    float bv = bih[col] + bhh[col];
#pragma unroll
    for (int i = 0; i < 16; ++i) acc[g][i] = bv;
  }
  // X @ Wih^T
#pragma unroll
  for (int ks = 0; ks < 8; ++ks) {
    int a_off = (m << 7) + ((((ks * 2 + hf) ^ (m & 15))) << 3);
    half8 ah = *(const half8*)(Xh + a_off);
    half8 al = *(const half8*)(Xl + a_off);
#pragma unroll
    for (int g = 0; g < 4; ++g) {
      int nt = (g << 2) + w;
      int boff = ((nt * 8 + ks) * 64 + lane) * 8;
      half8 bh = *(const half8*)(Wxh + boff);
      half8 bl = *(const half8*)(Wxl + boff);
      acc[g] = __builtin_amdgcn_mfma_f32_32x32x16_f16(ah, bh, acc[g], 0, 0, 0);
      acc[g] = __builtin_amdgcn_mfma_f32_32x32x16_f16(ah, bl, acc[g], 0, 0, 0);
      acc[g] = __builtin_amdgcn_mfma_f32_32x32x16_f16(al, bh, acc[g], 0, 0, 0);
    }
  }
  // h @ Whh^T
#pragma unroll
  for (int ks = 0; ks < 8; ++ks) {
    int a_off = (m << 7) + ((((ks * 2 + hf) ^ (m & 15))) << 3);
    half8 ah = *(const half8*)(Hh + a_off);
    half8 al = *(const half8*)(Hl + a_off);
#pragma unroll
    for (int g = 0; g < 4; ++g) {
      int nt = (g << 2) + w;
      int boff = ((nt * 8 + ks) * 64 + lane) * 8;
      half8 bh = *(const half8*)(Whh + boff);
      half8 bl = *(const half8*)(Whl + boff);
      acc[g] = __builtin_amdgcn_mfma_f32_32x32x16_f16(ah, bh, acc[g], 0, 0, 0);
      acc[g] = __builtin_amdgcn_mfma_f32_32x32x16_f16(ah, bl, acc[g], 0, 0, 0);
      acc[g] = __builtin_amdgcn_mfma_f32_32x32x16_f16(al, bh, acc[g], 0, 0, 0);
    }
  }
  // elementwise: gate order i,f,g,o
  int cw = (w << 5) + (lane & 31);
  int rbase = (lane >> 5) << 2;
#pragma unroll
  for (int reg = 0; reg < 16; ++reg) {
    int row = rb + (reg & 3) + ((reg >> 2) << 3) + rbase;
    if (row < M) {
      float iv = sigf(acc[0][reg]);
      float fv = sigf(acc[1][reg]);
      float gv = tanh_fast(acc[2][reg]);
      float ov = sigf(acc[3][reg]);
      size_t o = (size_t)row * DIM + cw;
      float cn = fv * cbuf[o] + iv * gv;
      cbuf[o] = cn;
      hbuf[o] = ov * tanh_fast(cn);
    }
  }
}

// ---------------- final vote MLP (fp32, runs once) ----------------
__device__ __forceinline__ void tile_gemm(const float* S, const float* __restrict__ W,
                                          int colB, int rowB, float acc[4][4]) {
#pragma unroll 4
  for (int kc = 0; kc < DIM; kc += 4) {
    float4 xv[4], wv[4];
#pragma unroll
    for (int r = 0; r < 4; ++r) xv[r] = *(const float4*)(S + (rowB + r) * DIM + kc);
#pragma unroll
    for (int c = 0; c < 4; ++c) wv[c] = *(const float4*)(W + (size_t)(colB + c) * DIM + kc);
#pragma unroll
    for (int r = 0; r < 4; ++r)
#pragma unroll
      for (int c = 0; c < 4; ++c)
        acc[r][c] += xv[r].x * wv[c].x + xv[r].y * wv[c].y + xv[r].z * wv[c].z + xv[r].w * wv[c].w;
  }
}

__device__ __forceinline__ void layer_lds(const float* Sin, float* Sout,
                                          const float* __restrict__ W, const float* __restrict__ B,
                                          bool relu, int colB, int rowB) {
  float acc[4][4];
#pragma unroll
  for (int r = 0; r < 4; ++r)
#pragma unroll
    for (int cc = 0; cc < 4; ++cc) acc[r][cc] = B[colB + cc];
  tile_gemm(Sin, W, colB, rowB, acc);
#pragma unroll
  for (int r = 0; r < 4; ++r) {
    float4 v;
    v.x = acc[r][0]; v.y = acc[r][1]; v.z = acc[r][2]; v.w = acc[r][3];
    if (relu) { v.x = fmaxf(v.x, 0.f); v.y = fmaxf(v.y, 0.f); v.z = fmaxf(v.z, 0.f); v.w = fmaxf(v.w, 0.f); }
    *(float4*)&Sout[(rowB + r) * DIM + colB] = v;
  }
  __syncthreads();
}

__global__ __launch_bounds__(256) void vote_kernel(
    const float* __restrict__ X, int M,
    const float* __restrict__ W1, const float* __restrict__ b1,
    const float* __restrict__ W2, const float* __restrict__ b2,
    const float* __restrict__ W3, const float* __restrict__ b3,
    float* __restrict__ out) {
  __shared__ float Xs[32 * DIM];
  __shared__ float Ys[32 * DIM];
  int tid = threadIdx.x;
  int rb = blockIdx.x * 32;
  int mrows = M - rb; if (mrows > 32) mrows = 32;
  {
    const float4* src = (const float4*)(X + (size_t)rb * DIM);
    float4* dst = (float4*)Xs;
    int nf4 = mrows * (DIM / 4);
    for (int t = tid; t < 32 * (DIM / 4); t += 256) {
      float4 v;
      if (t < nf4) v = src[t];
      else { v.x = v.y = v.z = v.w = 0.f; }
      dst[t] = v;
    }
  }
  __syncthreads();
  int tx = tid & 31, ty = tid >> 5;
  int colB = tx * 4, rowB = ty * 4;
  layer_lds(Xs, Ys, W1, b1, true, colB, rowB);
  layer_lds(Ys, Xs, W2, b2, true, colB, rowB);
  if (tid < 32) {
    int gr = rb + tid;
    if (gr < M) {
      float s = b3[0];
      for (int k = 0; k < DIM; ++k) s += Xs[tid * DIM + k] * W3[k];
      out[gr] = s;
    }
  }
}

extern "C" void kernel_launch(void* const* d_in, const int* in_sizes, int n_in,
                              void* d_out, int out_size, void* d_ws, size_t ws_size,
                              hipStream_t stream) {
  const float* adj    = (const float*)d_in[0];
  const int*   values = (const int*)d_in[1];
  const int N       = in_sizes[1];                  // 9000
  const int n_nodes = in_sizes[0] / N;              // 8000
  const int n_vars  = N - n_nodes;                  // 1000

  const float* true_W  = (const float*)d_in[3];
  const float* true_b  = (const float*)d_in[4];
  const float* false_W = (const float*)d_in[5];
  const float* false_b = (const float*)d_in[6];
  const float* cm_W1 = (const float*)d_in[7];
  const float* cm_b1 = (const float*)d_in[8];
  const float* cm_W2 = (const float*)d_in[9];
  const float* cm_b2 = (const float*)d_in[10];
  const float* cm_W3 = (const float*)d_in[11];
  const float* cm_b3 = (const float*)d_in[12];
  const float* pm_W1 = (const float*)d_in[13];
  const float* pm_b1 = (const float*)d_in[14];
  const float* pm_W2 = (const float*)d_in[15];
  const float* pm_b2 = (const float*)d_in[16];
  const float* pm_W3 = (const float*)d_in[17];
  const float* pm_b3 = (const float*)d_in[18];
  const float* vv_W1 = (const float*)d_in[19];
  const float* vv_b1 = (const float*)d_in[20];
  const float* vv_W2 = (const float*)d_in[21];
  const float* vv_b2 = (const float*)d_in[22];
  const float* vv_W3 = (const float*)d_in[23];
  const float* vv_b3 = (const float*)d_in[24];
  const float* vu_Wih = (const float*)d_in[25];
  const float* vu_Whh = (const float*)d_in[26];
  const float* vu_bih = (const float*)d_in[27];
  const float* vu_bhh = (const float*)d_in[28];
  const float* nu_Wih = (const float*)d_in[29];
  const float* nu_Whh = (const float*)d_in[30];
  const float* nu_bih = (const float*)d_in[31];
  const float* nu_bhh = (const float*)d_in[32];

  uintptr_t p = (uintptr_t)d_ws;
  auto take = [&](size_t bytes) -> void* {
    uintptr_t cur = (p + 255) & ~(uintptr_t)255;
    p = cur + bytes;
    return (void*)cur;
  };
  float* h  = (float*)take((size_t)N * DIM * sizeof(float));
  float* cb = (float*)take((size_t)N * DIM * sizeof(float));
  float* va = (float*)take((size_t)N * DIM * sizeof(float));
  int* row_ptr = (int*)take((size_t)(n_nodes + 1) * sizeof(int));
  int* col_ptr = (int*)take((size_t)(N + 1) * sizeof(int));
  int* cnts    = (int*)take((size_t)2 * (n_nodes + N) * sizeof(int));
  int* row_cnt  = cnts;
  int* col_cnt  = cnts + n_nodes;
  int* row_fill = cnts + n_nodes + N;
  int* col_fill = cnts + 2 * n_nodes + N;
  int* col_idx = (int*)take((size_t)NNZ_CAP * sizeof(int));
  int* row_idx = (int*)take((size_t)NNZ_CAP * sizeof(int));

  // packed split-f16 weights (MFMA B-fragment order)
  const int SZ128 = DIM * DIM;         // 16384
  const int SZ512 = 4 * DIM * DIM;     // 65536
  size_t tot_pack = (size_t)6 * SZ128 + (size_t)4 * SZ512;
  _Float16* packh = (_Float16*)take(tot_pack * sizeof(_Float16));
  _Float16* packl = (_Float16*)take(tot_pack * sizeof(_Float16));
  size_t off = 0;
  auto sub = [&](size_t n) { size_t o = off; off += n; return o; };
  size_t o_cm1 = sub(SZ128), o_cm2 = sub(SZ128), o_cm3 = sub(SZ128);
  size_t o_pm1 = sub(SZ128), o_pm2 = sub(SZ128), o_pm3 = sub(SZ128);
  size_t o_vux = sub(SZ512), o_vuh = sub(SZ512);
  size_t o_nux = sub(SZ512), o_nuh = sub(SZ512);

  hipMemsetAsync(cnts, 0, (size_t)2 * (n_nodes + N) * sizeof(int), stream);
  dim3 cgrid(n_nodes, (N + 255) / 256);
  count_nz_kernel<<<cgrid, 256, 0, stream>>>(adj, row_cnt, col_cnt, N);
  scan_kernel<<<1, 256, 0, stream>>>(row_cnt, row_ptr, n_nodes);
  scan_kernel<<<1, 256, 0, stream>>>(col_cnt, col_ptr, N);
  fill_nz_kernel<<<cgrid, 256, 0, stream>>>(adj, row_ptr, col_ptr, row_fill, col_fill,
                                            col_idx, row_idx, N);
  init_hc_kernel<<<(N * DIM + 255) / 256, 256, 0, stream>>>(values, true_W, true_b,
                                                            false_W, false_b, h, cb, N);

  auto pack = [&](const float* src, int out_dim, size_t o) {
    pack_w_kernel<<<(out_dim * DIM + 255) / 256, 256, 0, stream>>>(src, out_dim,
                                                                   packh + o, packl + o);
  };
  pack(cm_W1, DIM, o_cm1); pack(cm_W2, DIM, o_cm2); pack(cm_W3, DIM, o_cm3);
  pack(pm_W1, DIM, o_pm1); pack(pm_W2, DIM, o_pm2); pack(pm_W3, DIM, o_pm3);
  pack(vu_Wih, 4 * DIM, o_vux); pack(vu_Whh, 4 * DIM, o_vuh);
  pack(nu_Wih, 4 * DIM, o_nux); pack(nu_Whh, 4 * DIM, o_nuh);

  int mb_N = (N + 31) / 32, mb_n = (n_nodes + 31) / 32;
  for (int r = 0; r < NROUNDS; ++r) {
    mlp3_mfma<<<mb_N, 256, 0, stream>>>(h, N,
        packh + o_cm1, packl + o_cm1, cm_b1,
        packh + o_cm2, packl + o_cm2, cm_b2,
        packh + o_cm3, packl + o_cm3, cm_b3, va);
    lstm_mfma<<<mb_n, 256, 0, stream>>>(row_ptr, col_idx, va, h, cb, n_nodes,
        packh + o_vux, packl + o_vux, packh + o_vuh, packl + o_vuh, vu_bih, vu_bhh);
    mlp3_mfma<<<mb_n, 256, 0, stream>>>(h, n_nodes,
        packh + o_pm1, packl + o_pm1, pm_b1,
        packh + o_pm2, packl + o_pm2, pm_b2,
        packh + o_pm3, packl + o_pm3, pm_b3, va);
    lstm_mfma<<<mb_N, 256, 0, stream>>>(col_ptr, row_idx, va, h, cb, N,
        packh + o_nux, packl + o_nux, packh + o_nuh, packl + o_nuh, nu_bih, nu_bhh);
  }
  vote_kernel<<<(n_vars + 31) / 32, 256, 0, stream>>>(h + (size_t)n_nodes * DIM, n_vars,
      vv_W1, vv_b1, vv_W2, vv_b2, vv_W3, vv_b3, (float*)d_out);
}